// Round 2
// baseline (2427.000 us; speedup 1.0000x reference)
//
#include <hip/hip_runtime.h>

#define NN 50000
#define EE 400000
#define EP 450000
#define FIN 64
#define HH 256
#define GG 64
#define NGFD 32

// ---------------- CSR build ----------------
__global__ void k_init_deg(int* deg) {
  int i = blockIdx.x * 256 + threadIdx.x;
  if (i < NN) deg[i] = 1;  // self loop
}
__global__ void k_hist(const int* __restrict__ dst, int* __restrict__ deg) {
  int e = blockIdx.x * 256 + threadIdx.x;
  if (e < EE) atomicAdd(&deg[dst[e]], 1);
}
__global__ void k_scan1(const int* __restrict__ deg, int* __restrict__ offs, int* __restrict__ aux) {
  __shared__ int sd[256];
  int b = blockIdx.x, t = threadIdx.x;
  int base = b * 1024 + t * 4;
  int v0 = 0, v1 = 0, v2 = 0, v3 = 0;
  if (base + 0 < NN) v0 = deg[base + 0];
  if (base + 1 < NN) v1 = deg[base + 1];
  if (base + 2 < NN) v2 = deg[base + 2];
  if (base + 3 < NN) v3 = deg[base + 3];
  sd[t] = v0 + v1 + v2 + v3;
  __syncthreads();
  for (int off = 1; off < 256; off <<= 1) {
    int x = (t >= off) ? sd[t - off] : 0;
    __syncthreads();
    sd[t] += x;
    __syncthreads();
  }
  if (t == 255) aux[b] = sd[255];
  int run = (t == 0) ? 0 : sd[t - 1];
  if (base + 0 < NN) offs[base + 0] = run; run += v0;
  if (base + 1 < NN) offs[base + 1] = run; run += v1;
  if (base + 2 < NN) offs[base + 2] = run; run += v2;
  if (base + 3 < NN) offs[base + 3] = run;
}
__global__ void k_scan2(int* aux, int nb) {
  if (threadIdx.x == 0 && blockIdx.x == 0) {
    int s = 0;
    for (int i = 0; i < nb; ++i) { int t = aux[i]; aux[i] = s; s += t; }
    aux[nb] = s;
  }
}
__global__ void k_scan3(int* __restrict__ offs, const int* __restrict__ aux) {
  int b = blockIdx.x, t = threadIdx.x;
  int base = b * 1024 + t * 4;
  int add = aux[b];
  #pragma unroll
  for (int i = 0; i < 4; ++i)
    if (base + i < NN) offs[base + i] += add;
  if (b == 0 && t == 0) offs[NN] = aux[gridDim.x];
}
__global__ void k_scatter(const int* __restrict__ srcA, const int* __restrict__ dstA,
                          int* __restrict__ cur, int* __restrict__ ssrc) {
  int e = blockIdx.x * 256 + threadIdx.x;
  if (e < EE) { int p = atomicAdd(&cur[dstA[e]], 1); ssrc[p] = srcA[e]; }
}
__global__ void k_scatter_self(int* __restrict__ cur, int* __restrict__ ssrc) {
  int i = blockIdx.x * 256 + threadIdx.x;
  if (i < NN) { int p = atomicAdd(&cur[i], 1); ssrc[p] = i; }
}

// ---------------- GEMM: C[M,256] = A[M,K] @ B[K,256] (+bias) ----------------
__global__ __launch_bounds__(256) void k_gemm(const float* __restrict__ A, const float* __restrict__ B,
                                              const float* __restrict__ bias, float* __restrict__ C,
                                              int M, int K) {
  __shared__ float As[16][136];   // [kk][row], padded
  __shared__ float Bs[16][128];   // [kk][col]
  int tid = threadIdx.x;
  int tx = tid & 15, ty = tid >> 4;
  int row0 = blockIdx.x * 128, col0 = blockIdx.y * 128;
  float acc[8][8];
  #pragma unroll
  for (int i = 0; i < 8; ++i)
    #pragma unroll
    for (int j = 0; j < 8; ++j) acc[i][j] = 0.f;

  for (int k0 = 0; k0 < K; k0 += 16) {
    #pragma unroll
    for (int i = 0; i < 8; ++i) {           // A tile 128x16
      int idx = tid + i * 256;
      int r = idx >> 4, kk = idx & 15;
      int gr = row0 + r;
      As[kk][r] = (gr < M) ? A[(size_t)gr * K + k0 + kk] : 0.f;
    }
    #pragma unroll
    for (int i = 0; i < 8; ++i) {           // B tile 16x128
      int idx = tid + i * 256;
      int r = idx >> 7, c = idx & 127;
      Bs[r][c] = B[(size_t)(k0 + r) * HH + col0 + c];
    }
    __syncthreads();
    #pragma unroll
    for (int kk = 0; kk < 16; ++kk) {
      float a[8], bb[8];
      *(float4*)&a[0]  = *(const float4*)&As[kk][ty * 8];
      *(float4*)&a[4]  = *(const float4*)&As[kk][ty * 8 + 4];
      *(float4*)&bb[0] = *(const float4*)&Bs[kk][tx * 8];
      *(float4*)&bb[4] = *(const float4*)&Bs[kk][tx * 8 + 4];
      #pragma unroll
      for (int i = 0; i < 8; ++i)
        #pragma unroll
        for (int j = 0; j < 8; ++j) acc[i][j] += a[i] * bb[j];
    }
    __syncthreads();
  }
  float bv[8];
  #pragma unroll
  for (int j = 0; j < 8; ++j) bv[j] = bias ? bias[col0 + tx * 8 + j] : 0.f;
  #pragma unroll
  for (int i = 0; i < 8; ++i) {
    int gr = row0 + ty * 8 + i;
    if (gr < M) {
      float4 o0, o1;
      o0.x = acc[i][0] + bv[0]; o0.y = acc[i][1] + bv[1];
      o0.z = acc[i][2] + bv[2]; o0.w = acc[i][3] + bv[3];
      o1.x = acc[i][4] + bv[4]; o1.y = acc[i][5] + bv[5];
      o1.z = acc[i][6] + bv[6]; o1.w = acc[i][7] + bv[7];
      float* cp = C + (size_t)gr * HH + col0 + tx * 8;
      *(float4*)cp = o0;
      *(float4*)(cp + 4) = o1;
    }
  }
}

// ---------------- attention dots: as/ad [N,8] ----------------
__global__ void k_attdot(const float* __restrict__ hp, const float* __restrict__ a_s,
                         const float* __restrict__ a_d, float* __restrict__ asn,
                         float* __restrict__ adn) {
  int n = blockIdx.x, t = threadIdx.x;  // 256 threads = one row
  float v = hp[(size_t)n * HH + t];
  float ps = v * a_s[t], pd = v * a_d[t];
  #pragma unroll
  for (int off = 16; off >= 1; off >>= 1) {
    ps += __shfl_xor(ps, off);
    pd += __shfl_xor(pd, off);
  }
  if ((t & 31) == 0) {
    int h = t >> 5;
    asn[n * 8 + h] = ps;
    adn[n * 8 + h] = pd;
  }
}

// ---------------- GAT edge softmax + aggregate: one wave per dst node ----------------
__global__ __launch_bounds__(256) void k_gat_agg(const int* __restrict__ offs, const int* __restrict__ ssrc,
                                                 const float* __restrict__ asn, const float* __restrict__ adn,
                                                 const float* __restrict__ hp, const float* __restrict__ bias,
                                                 float* __restrict__ outp) {
  int lane = threadIdx.x & 63;
  int n = blockIdx.x * 4 + (threadIdx.x >> 6);
  if (n >= NN) return;
  int hd = lane >> 3;                   // head for channels lane*4..lane*4+3
  float adh = adn[n * 8 + hd];
  int e0 = offs[n], e1 = offs[n + 1];
  // pass 1: online max + denominator
  float m = -1e30f, den = 0.f;
  for (int k = e0; k < e1; ++k) {
    int s = ssrc[k];
    float e = asn[s * 8 + hd] + adh;
    e = (e > 0.f) ? e : 0.2f * e;
    if (e > m) { den *= __expf(m - e); m = e; }
    den += __expf(e - m);
  }
  float rden = 1.f / den;
  // pass 2: weighted aggregate
  float4 acc = make_float4(0.f, 0.f, 0.f, 0.f);
  for (int k = e0; k < e1; ++k) {
    int s = ssrc[k];
    float e = asn[s * 8 + hd] + adh;
    e = (e > 0.f) ? e : 0.2f * e;
    float al = __expf(e - m) * rden;
    float4 hv = *reinterpret_cast<const float4*>(hp + (size_t)s * HH + lane * 4);
    acc.x += al * hv.x; acc.y += al * hv.y; acc.z += al * hv.z; acc.w += al * hv.w;
  }
  float4 bb = *reinterpret_cast<const float4*>(bias + lane * 4);
  float4 o = make_float4(acc.x + bb.x, acc.y + bb.y, acc.z + bb.z, acc.w + bb.w);
  *reinterpret_cast<float4*>(outp + (size_t)n * HH + lane * 4) = o;
}

// ---------------- BN over N rows, 256 cols ----------------
__global__ void k_colstats(const float* __restrict__ x, float* __restrict__ stats) {
  int c = threadIdx.x;
  int r0 = blockIdx.x * 256;
  int r1 = min(r0 + 256, NN);
  float s = 0.f, q = 0.f;
  for (int r = r0; r < r1; ++r) {
    float v = x[(size_t)r * HH + c];
    s += v; q += v * v;
  }
  atomicAdd(&stats[c], s);
  atomicAdd(&stats[HH + c], q);
}
__global__ void k_bn_apply(const float* __restrict__ x, const float* __restrict__ stats,
                           const float* __restrict__ g, const float* __restrict__ b,
                           const float* res, float* y) {
  size_t i = ((size_t)blockIdx.x * 256 + threadIdx.x) * 4;
  if (i >= (size_t)NN * HH) return;
  float4 v = *reinterpret_cast<const float4*>(x + i);
  int c = (int)(i & 255);
  const float invN = 1.f / (float)NN;
  float vv[4] = {v.x, v.y, v.z, v.w};
  float o[4];
  #pragma unroll
  for (int j = 0; j < 4; ++j) {
    int cc = c + j;
    float mean = stats[cc] * invN;
    float var = stats[HH + cc] * invN - mean * mean;
    float rs = rsqrtf(var + 1e-5f);
    float val = (vv[j] - mean) * rs * g[cc] + b[cc];
    val = fmaxf(val, 0.f);
    if (res) val += res[i + j];
    o[j] = val;
  }
  *reinterpret_cast<float4*>(y + i) = make_float4(o[0], o[1], o[2], o[3]);
}

// ---------------- pooling ----------------
__global__ void k_count(const int* __restrict__ batch, int* __restrict__ cnt) {
  int i = blockIdx.x * 256 + threadIdx.x;
  if (i < NN) atomicAdd(&cnt[batch[i]], 1);
}
__global__ void k_pool(const float* __restrict__ h, const int* __restrict__ batch,
                       float* __restrict__ gsum, float* __restrict__ gmax) {
  int c = threadIdx.x;
  int r0 = blockIdx.x * 512, r1 = min(r0 + 512, NN);
  if (r0 >= r1) return;
  int curg = batch[r0];
  float s = 0.f, mx = 0.f;   // h >= 0 after ReLU
  for (int r = r0; r < r1; ++r) {
    int g = batch[r];
    if (g != curg) {
      atomicAdd(&gsum[curg * HH + c], s);
      atomicMax((int*)&gmax[curg * HH + c], __float_as_int(mx));
      s = 0.f; mx = 0.f; curg = g;
    }
    float v = h[(size_t)r * HH + c];
    s += v; mx = fmaxf(mx, v);
  }
  atomicAdd(&gsum[curg * HH + c], s);
  atomicMax((int*)&gmax[curg * HH + c], __float_as_int(mx));
}
__global__ void k_buildz(const float* __restrict__ gsum, const float* __restrict__ gmax,
                         const int* __restrict__ cnt, const float* __restrict__ gf,
                         float* __restrict__ z) {
  int g = blockIdx.x;
  for (int c = threadIdx.x; c < 800; c += 256) {
    float v;
    if (c < 256)      v = gsum[g * HH + c] / (float)cnt[g];
    else if (c < 512) v = gmax[g * HH + (c - 256)];
    else if (c < 768) v = gsum[g * HH + (c - 512)];
    else              v = gf[g * NGFD + (c - 768)];
    z[g * 800 + c] = v;
  }
}

// ---------------- classifier: linear + BN(64) + relu, one column per block ----------------
__global__ void k_mlp_bn(const float* __restrict__ zin, const float* __restrict__ W,
                         const float* __restrict__ bias, const float* __restrict__ g,
                         const float* __restrict__ be, float* __restrict__ zout,
                         int K, int OC) {
  int j = blockIdx.x;
  int i = threadIdx.x;  // 64 threads = rows
  float acc = bias[j];
  for (int k = 0; k < K; ++k) acc += zin[i * K + k] * W[k * OC + j];
  float s = acc;
  #pragma unroll
  for (int off = 32; off >= 1; off >>= 1) s += __shfl_xor(s, off);
  float mu = s * (1.f / 64.f);
  float d = acc - mu;
  float q = d * d;
  #pragma unroll
  for (int off = 32; off >= 1; off >>= 1) q += __shfl_xor(q, off);
  float var = q * (1.f / 64.f);
  float val = d * rsqrtf(var + 1e-5f) * g[j] + be[j];
  zout[i * OC + j] = fmaxf(val, 0.f);
}
__global__ void k_final(const float* __restrict__ z2, const float* __restrict__ W3,
                        const float* __restrict__ b3, float* __restrict__ out) {
  int t = threadIdx.x;
  if (t >= 128) return;
  int i = t >> 1, j = t & 1;
  float acc = b3[j];
  for (int k = 0; k < 256; ++k) acc += z2[i * 256 + k] * W3[k * 2 + j];
  out[i * 2 + j] = acc;
}

extern "C" void kernel_launch(void* const* d_in, const int* in_sizes, int n_in,
                              void* d_out, int out_size, void* d_ws, size_t ws_size,
                              hipStream_t stream) {
  const float* x      = (const float*)d_in[0];
  const int*   ei     = (const int*)d_in[1];
  const int*   batch  = (const int*)d_in[2];
  const float* gf     = (const float*)d_in[3];
  const float* W_enc  = (const float*)d_in[4];
  const float* b_enc  = (const float*)d_in[5];
  const float* g_enc  = (const float*)d_in[6];
  const float* be_enc = (const float*)d_in[7];
  const float* Wg     = (const float*)d_in[8];
  const float* att_s  = (const float*)d_in[9];
  const float* att_d  = (const float*)d_in[10];
  const float* bg     = (const float*)d_in[11];
  const float* bn_g   = (const float*)d_in[12];
  const float* bn_b   = (const float*)d_in[13];
  const float* W1     = (const float*)d_in[14];
  const float* b1     = (const float*)d_in[15];
  const float* g1     = (const float*)d_in[16];
  const float* be1    = (const float*)d_in[17];
  const float* W2     = (const float*)d_in[18];
  const float* b2     = (const float*)d_in[19];
  const float* g2     = (const float*)d_in[20];
  const float* be2    = (const float*)d_in[21];
  const float* W3     = (const float*)d_in[22];
  const float* b3     = (const float*)d_in[23];
  float* out = (float*)d_out;

  char* w = (char*)d_ws;
  auto alloc = [&](size_t bytes) { char* p = w; w += (bytes + 255) & ~(size_t)255; return p; };
  float* A    = (float*)alloc((size_t)NN * HH * 4);
  float* Bb   = (float*)alloc((size_t)NN * HH * 4);
  float* Cc   = (float*)alloc((size_t)NN * HH * 4);
  float* asn  = (float*)alloc((size_t)NN * 8 * 4);
  float* adn  = (float*)alloc((size_t)NN * 8 * 4);
  int*   deg  = (int*)alloc((size_t)NN * 4);
  int*   offs = (int*)alloc((size_t)(NN + 1) * 4);
  int*   cur  = (int*)alloc((size_t)NN * 4);
  int*   ssrc = (int*)alloc((size_t)EP * 4);
  float* stats= (float*)alloc(512 * 4);
  int*   aux  = (int*)alloc(64 * 4);
  int*   cnt  = (int*)alloc(GG * 4);
  float* gsum = (float*)alloc((size_t)GG * HH * 4);
  float* gmax = (float*)alloc((size_t)GG * HH * 4);
  float* zb   = (float*)alloc((size_t)GG * 800 * 4);
  float* z1   = (float*)alloc((size_t)GG * 512 * 4);
  float* z2   = (float*)alloc((size_t)GG * 256 * 4);

  const int* e_src = ei;
  const int* e_dst = ei + EE;

  // ---- CSR build (per call: no cached state) ----
  k_init_deg<<<196, 256, 0, stream>>>(deg);
  k_hist<<<1563, 256, 0, stream>>>(e_dst, deg);
  k_scan1<<<49, 256, 0, stream>>>(deg, offs, aux);
  k_scan2<<<1, 64, 0, stream>>>(aux, 49);
  k_scan3<<<49, 256, 0, stream>>>(offs, aux);
  hipMemcpyAsync(cur, offs, (size_t)NN * 4, hipMemcpyDeviceToDevice, stream);
  k_scatter<<<1563, 256, 0, stream>>>(e_src, e_dst, cur, ssrc);
  k_scatter_self<<<196, 256, 0, stream>>>(cur, ssrc);

  dim3 gemmGrid((NN + 127) / 128, 2);

  // ---- node encoder ----
  k_gemm<<<gemmGrid, 256, 0, stream>>>(x, W_enc, b_enc, Bb, NN, FIN);
  hipMemsetAsync(stats, 0, 512 * 4, stream);
  k_colstats<<<196, 256, 0, stream>>>(Bb, stats);
  k_bn_apply<<<12500, 256, 0, stream>>>(Bb, stats, g_enc, be_enc, nullptr, A);

  // ---- GAT layers ----
  for (int l = 0; l < 4; ++l) {
    k_gemm<<<gemmGrid, 256, 0, stream>>>(A, Wg + (size_t)l * HH * HH, nullptr, Bb, NN, HH);
    k_attdot<<<NN, 256, 0, stream>>>(Bb, att_s + l * HH, att_d + l * HH, asn, adn);
    k_gat_agg<<<(NN + 3) / 4, 256, 0, stream>>>(offs, ssrc, asn, adn, Bb, bg + l * HH, Cc);
    hipMemsetAsync(stats, 0, 512 * 4, stream);
    k_colstats<<<196, 256, 0, stream>>>(Cc, stats);
    k_bn_apply<<<12500, 256, 0, stream>>>(Cc, stats, bn_g + l * HH, bn_b + l * HH,
                                          (l == 2) ? A : nullptr, A);
  }

  // ---- pooling + classifier ----
  hipMemsetAsync(cnt, 0, GG * 4, stream);
  hipMemsetAsync(gsum, 0, (size_t)GG * HH * 4, stream);
  hipMemsetAsync(gmax, 0, (size_t)GG * HH * 4, stream);
  k_count<<<196, 256, 0, stream>>>(batch, cnt);
  k_pool<<<(NN + 511) / 512, 256, 0, stream>>>(A, batch, gsum, gmax);
  k_buildz<<<GG, 256, 0, stream>>>(gsum, gmax, cnt, gf, zb);
  k_mlp_bn<<<512, 64, 0, stream>>>(zb, W1, b1, g1, be1, z1, 800, 512);
  k_mlp_bn<<<256, 64, 0, stream>>>(z1, W2, b2, g2, be2, z2, 512, 256);
  k_final<<<1, 128, 0, stream>>>(z2, W3, b3, out);
}

// Round 5
// 1844.898 us; speedup vs baseline: 1.3155x; 1.3155x over previous
//
#include <hip/hip_runtime.h>

#define NN 50000
#define MPAD 50048
#define EE 400000
#define EP 450000
#define FIN 64
#define HH 256
#define GG 64
#define NGFD 32

typedef __attribute__((ext_vector_type(8))) short bf16x8;
typedef __attribute__((ext_vector_type(4))) float f32x4;

__device__ __forceinline__ float bf2f(unsigned short s) {
  return __uint_as_float(((unsigned int)s) << 16);
}
__device__ __forceinline__ unsigned short f2bf(float f) {
  unsigned int u = __float_as_uint(f);
  u += 0x7fffu + ((u >> 16) & 1u);
  return (unsigned short)(u >> 16);
}

// ---------------- CSR build ----------------
__global__ void k_init_deg(int* deg) {
  int i = blockIdx.x * 256 + threadIdx.x;
  if (i < NN) deg[i] = 1;  // self loop
}
__global__ void k_hist(const int* __restrict__ dst, int* __restrict__ deg) {
  int e = blockIdx.x * 256 + threadIdx.x;
  if (e < EE) atomicAdd(&deg[dst[e]], 1);
}
__global__ void k_scan1(const int* __restrict__ deg, int* __restrict__ offs, int* __restrict__ aux) {
  __shared__ int sd[256];
  int b = blockIdx.x, t = threadIdx.x;
  int base = b * 1024 + t * 4;
  int v0 = 0, v1 = 0, v2 = 0, v3 = 0;
  if (base + 0 < NN) v0 = deg[base + 0];
  if (base + 1 < NN) v1 = deg[base + 1];
  if (base + 2 < NN) v2 = deg[base + 2];
  if (base + 3 < NN) v3 = deg[base + 3];
  sd[t] = v0 + v1 + v2 + v3;
  __syncthreads();
  for (int off = 1; off < 256; off <<= 1) {
    int x = (t >= off) ? sd[t - off] : 0;
    __syncthreads();
    sd[t] += x;
    __syncthreads();
  }
  if (t == 255) aux[b] = sd[255];
  int run = (t == 0) ? 0 : sd[t - 1];
  if (base + 0 < NN) offs[base + 0] = run; run += v0;
  if (base + 1 < NN) offs[base + 1] = run; run += v1;
  if (base + 2 < NN) offs[base + 2] = run; run += v2;
  if (base + 3 < NN) offs[base + 3] = run;
}
__global__ void k_scan2(int* aux, int nb) {
  if (threadIdx.x == 0 && blockIdx.x == 0) {
    int s = 0;
    for (int i = 0; i < nb; ++i) { int t = aux[i]; aux[i] = s; s += t; }
    aux[nb] = s;
  }
}
__global__ void k_scan3(int* __restrict__ offs, const int* __restrict__ aux) {
  int b = blockIdx.x, t = threadIdx.x;
  int base = b * 1024 + t * 4;
  int add = aux[b];
  #pragma unroll
  for (int i = 0; i < 4; ++i)
    if (base + i < NN) offs[base + i] += add;
  if (b == 0 && t == 0) offs[NN] = aux[gridDim.x];
}
__global__ void k_scatter(const int* __restrict__ srcA, const int* __restrict__ dstA,
                          int* __restrict__ cur, int* __restrict__ ssrc) {
  int e = blockIdx.x * 256 + threadIdx.x;
  if (e < EE) { int p = atomicAdd(&cur[dstA[e]], 1); ssrc[p] = srcA[e]; }
}
__global__ void k_scatter_self(int* __restrict__ cur, int* __restrict__ ssrc) {
  int i = blockIdx.x * 256 + threadIdx.x;
  if (i < NN) { int p = atomicAdd(&cur[i], 1); ssrc[p] = i; }
}

// ---------------- graph boundaries via binary search (batch is sorted) ----------------
__global__ void k_bounds(const int* __restrict__ batch, int* __restrict__ start) {
  int g = threadIdx.x;
  if (g > GG) return;
  int lo = 0, hi = NN;
  while (lo < hi) { int mid = (lo + hi) >> 1; if (batch[mid] < g) lo = mid + 1; else hi = mid; }
  start[g] = lo;
}

// ---------------- weight prep: W[K][N] f32 -> WT[N][K] bf16 ----------------
__global__ void k_prepW(const float* __restrict__ W, unsigned short* __restrict__ WT, int K, int N) {
  __shared__ float tile[32][33];
  int l = blockIdx.z;
  const float* Wp = W + (size_t)l * K * N;
  unsigned short* Tp = WT + (size_t)l * K * N;
  int n0 = blockIdx.x * 32, k0 = blockIdx.y * 32;
  int tx = threadIdx.x & 31, ty = threadIdx.x >> 5;  // 8 row-groups
  #pragma unroll
  for (int rr = 0; rr < 32; rr += 8) {
    int k = k0 + ty + rr, n = n0 + tx;
    if (k < K && n < N) tile[ty + rr][tx] = Wp[(size_t)k * N + n];
  }
  __syncthreads();
  #pragma unroll
  for (int rr = 0; rr < 32; rr += 8) {
    int n = n0 + ty + rr, k = k0 + tx;
    if (n < N && k < K) Tp[(size_t)n * K + k] = f2bf(tile[tx][ty + rr]);
  }
}

__global__ void k_cvt_x(const float* __restrict__ x, unsigned short* __restrict__ xb) {
  size_t i = ((size_t)blockIdx.x * 256 + threadIdx.x) * 4;
  if (i >= (size_t)NN * FIN) return;
  float4 v = *reinterpret_cast<const float4*>(x + i);
  ushort4 o;
  o.x = f2bf(v.x); o.y = f2bf(v.y); o.z = f2bf(v.z); o.w = f2bf(v.w);
  *reinterpret_cast<ushort4*>(xb + i) = o;
}

// ---------------- bf16 MFMA GEMM: C[MPAD,256] = A[MPAD,K] @ BT[256,K]^T ----------------
// 128x128 tile, 4 waves of 64x64, BK=64, global_load_lds w/ pre-swizzled source,
// XOR-swizzled ds_read_b128 (st_16x32-style: byte ^= (row&7)<<4).
__global__ __launch_bounds__(256) void k_mfma(const unsigned short* __restrict__ A,
                                              const unsigned short* __restrict__ BT,
                                              unsigned short* __restrict__ C, int K) {
  __shared__ unsigned short As[128 * 64];
  __shared__ unsigned short Bs[128 * 64];
  const int t = threadIdx.x;
  const int w = t >> 6, l = t & 63;
  const int row0 = blockIdx.x * 128;
  const int col0 = blockIdx.y * 128;
  const int wm = w & 1, wn = w >> 1;

  f32x4 acc[4][4];
  #pragma unroll
  for (int i = 0; i < 4; ++i)
    #pragma unroll
    for (int j = 0; j < 4; ++j) acc[i][j] = (f32x4){0.f, 0.f, 0.f, 0.f};

  const int lrow = w * 8 + (l >> 3);                      // row within 32-row round
  const int ksrc_sh = ((l & 7) ^ (lrow & 7)) << 3;        // source k offset in shorts (inverse swizzle)

  for (int k0 = 0; k0 < K; k0 += 64) {
    #pragma unroll
    for (int rd = 0; rd < 4; ++rd) {
      int r = rd * 32 + lrow;
      const unsigned short* ga = A + (size_t)(row0 + r) * K + k0 + ksrc_sh;
      __builtin_amdgcn_global_load_lds(
          (const __attribute__((address_space(1))) void*)ga,
          (__attribute__((address_space(3))) void*)(As + (size_t)(rd * 32 + w * 8) * 64),
          16, 0, 0);
    }
    #pragma unroll
    for (int rd = 0; rd < 4; ++rd) {
      int r = rd * 32 + lrow;
      const unsigned short* gb = BT + (size_t)(col0 + r) * K + k0 + ksrc_sh;
      __builtin_amdgcn_global_load_lds(
          (const __attribute__((address_space(1))) void*)gb,
          (__attribute__((address_space(3))) void*)(Bs + (size_t)(rd * 32 + w * 8) * 64),
          16, 0, 0);
    }
    __syncthreads();

    const char* AsB = (const char*)As;
    const char* BsB = (const char*)Bs;
    #pragma unroll
    for (int ks = 0; ks < 2; ++ks) {
      bf16x8 af[4], bfr[4];
      #pragma unroll
      for (int i = 0; i < 4; ++i) {
        int ar = wm * 64 + i * 16 + (l & 15);
        int ab = ar * 128 + ((ks * 64 + (l >> 4) * 16) ^ ((ar & 7) << 4));
        af[i] = *(const bf16x8*)(AsB + ab);
        int br = wn * 64 + i * 16 + (l & 15);
        int bb = br * 128 + ((ks * 64 + (l >> 4) * 16) ^ ((br & 7) << 4));
        bfr[i] = *(const bf16x8*)(BsB + bb);
      }
      #pragma unroll
      for (int i = 0; i < 4; ++i)
        #pragma unroll
        for (int j = 0; j < 4; ++j)
          acc[i][j] = __builtin_amdgcn_mfma_f32_16x16x32_bf16(af[i], bfr[j], acc[i][j], 0, 0, 0);
    }
    __syncthreads();
  }

  // epilogue: C/D layout col=lane&15, row=(lane>>4)*4+r
  #pragma unroll
  for (int i = 0; i < 4; ++i) {
    int rbase = row0 + wm * 64 + i * 16 + ((l >> 4) * 4);
    #pragma unroll
    for (int j = 0; j < 4; ++j) {
      int c = col0 + wn * 64 + j * 16 + (l & 15);
      #pragma unroll
      for (int r = 0; r < 4; ++r) {
        int rr = rbase + r;
        if (rr < NN) C[(size_t)rr * HH + c] = f2bf(acc[i][j][r]);
      }
    }
  }
}

// ---------------- attention dots from bf16 hp ----------------
__global__ void k_attdot(const unsigned short* __restrict__ hp, const float* __restrict__ a_s,
                         const float* __restrict__ a_d, float* __restrict__ asn,
                         float* __restrict__ adn) {
  int lane = threadIdx.x & 63;
  int n = blockIdx.x * 4 + (threadIdx.x >> 6);
  if (n >= NN) return;
  ushort4 v = *reinterpret_cast<const ushort4*>(hp + (size_t)n * HH + lane * 4);
  float4 s4 = *reinterpret_cast<const float4*>(a_s + lane * 4);
  float4 d4 = *reinterpret_cast<const float4*>(a_d + lane * 4);
  float x0 = bf2f(v.x), x1 = bf2f(v.y), x2 = bf2f(v.z), x3 = bf2f(v.w);
  float ps = x0 * s4.x + x1 * s4.y + x2 * s4.z + x3 * s4.w;
  float pd = x0 * d4.x + x1 * d4.y + x2 * d4.z + x3 * d4.w;
  ps += __shfl_xor(ps, 1); ps += __shfl_xor(ps, 2); ps += __shfl_xor(ps, 4);
  pd += __shfl_xor(pd, 1); pd += __shfl_xor(pd, 2); pd += __shfl_xor(pd, 4);
  if ((lane & 7) == 0) {
    asn[n * 8 + (lane >> 3)] = ps;
    adn[n * 8 + (lane >> 3)] = pd;
  }
}

// ---------------- GAT edge softmax + aggregate (bf16 gather) ----------------
__global__ __launch_bounds__(256) void k_gat_agg(const int* __restrict__ offs, const int* __restrict__ ssrc,
                                                 const float* __restrict__ asn, const float* __restrict__ adn,
                                                 const unsigned short* __restrict__ hp,
                                                 float* __restrict__ outp) {
  int lane = threadIdx.x & 63;
  int n = blockIdx.x * 4 + (threadIdx.x >> 6);
  if (n >= NN) return;
  int hd = lane >> 3;
  float adh = adn[n * 8 + hd];
  int e0 = offs[n], e1 = offs[n + 1];
  float m = -1e30f, den = 0.f;
  for (int k = e0; k < e1; ++k) {
    int s = ssrc[k];
    float e = asn[s * 8 + hd] + adh;
    e = (e > 0.f) ? e : 0.2f * e;
    if (e > m) { den *= __expf(m - e); m = e; }
    den += __expf(e - m);
  }
  float rden = 1.f / den;
  float4 acc = make_float4(0.f, 0.f, 0.f, 0.f);
  for (int k = e0; k < e1; ++k) {
    int s = ssrc[k];
    float e = asn[s * 8 + hd] + adh;
    e = (e > 0.f) ? e : 0.2f * e;
    float al = __expf(e - m) * rden;
    ushort4 hv = *reinterpret_cast<const ushort4*>(hp + (size_t)s * HH + lane * 4);
    acc.x += al * bf2f(hv.x); acc.y += al * bf2f(hv.y);
    acc.z += al * bf2f(hv.z); acc.w += al * bf2f(hv.w);
  }
  *reinterpret_cast<float4*>(outp + (size_t)n * HH + lane * 4) = acc;
}

// ---------------- BN stats (partials, no atomics) ----------------
__global__ void k_cstat_bf(const unsigned short* __restrict__ x, float* __restrict__ pst) {
  int c = threadIdx.x, b = blockIdx.x;
  int r0 = b * 256, r1 = min(r0 + 256, NN);
  float s = 0.f, q = 0.f;
  for (int r = r0; r < r1; ++r) {
    float v = bf2f(x[(size_t)r * HH + c]);
    s += v; q += v * v;
  }
  pst[b * 512 + c] = s;
  pst[b * 512 + 256 + c] = q;
}
__global__ void k_cstat_f32(const float* __restrict__ x, float* __restrict__ pst) {
  int c = threadIdx.x, b = blockIdx.x;
  int r0 = b * 256, r1 = min(r0 + 256, NN);
  float s = 0.f, q = 0.f;
  for (int r = r0; r < r1; ++r) {
    float v = x[(size_t)r * HH + c];
    s += v; q += v * v;
  }
  pst[b * 512 + c] = s;
  pst[b * 512 + 256 + c] = q;
}
__global__ void k_redstat(const float* __restrict__ pst, float* __restrict__ stats, int nb) {
  int c = blockIdx.x * 256 + threadIdx.x;  // 512 total
  float s = 0.f;
  for (int b = 0; b < nb; ++b) s += pst[b * 512 + c];
  stats[c] = s;
}

// ---------------- BN apply + relu (+res), writes f32 + bf16 ----------------
__global__ void k_bnap_bf(const unsigned short* __restrict__ x, const float* __restrict__ stats,
                          const float* __restrict__ g, const float* __restrict__ b,
                          float* __restrict__ y, unsigned short* __restrict__ ybf) {
  size_t i = ((size_t)blockIdx.x * 256 + threadIdx.x) * 4;
  if (i >= (size_t)NN * HH) return;
  ushort4 v = *reinterpret_cast<const ushort4*>(x + i);
  int c = (int)(i & 255);
  const float invN = 1.f / (float)NN;
  float vv[4] = {bf2f(v.x), bf2f(v.y), bf2f(v.z), bf2f(v.w)};
  float4 yo; ushort4 bo;
  float o[4];
  #pragma unroll
  for (int j = 0; j < 4; ++j) {
    int cc = c + j;
    float mean = stats[cc] * invN;
    float var = stats[HH + cc] * invN - mean * mean;
    float rs = rsqrtf(var + 1e-5f);
    float val = (vv[j] - mean) * rs * g[cc] + b[cc];
    o[j] = fmaxf(val, 0.f);
  }
  yo.x = o[0]; yo.y = o[1]; yo.z = o[2]; yo.w = o[3];
  bo.x = f2bf(o[0]); bo.y = f2bf(o[1]); bo.z = f2bf(o[2]); bo.w = f2bf(o[3]);
  *reinterpret_cast<float4*>(y + i) = yo;
  *reinterpret_cast<ushort4*>(ybf + i) = bo;
}
__global__ void k_bnap_f32(const float* __restrict__ x, const float* __restrict__ stats,
                           const float* __restrict__ g, const float* __restrict__ b,
                           const float* res, float* y, unsigned short* __restrict__ ybf) {
  size_t i = ((size_t)blockIdx.x * 256 + threadIdx.x) * 4;
  if (i >= (size_t)NN * HH) return;
  float4 v = *reinterpret_cast<const float4*>(x + i);
  int c = (int)(i & 255);
  const float invN = 1.f / (float)NN;
  float vv[4] = {v.x, v.y, v.z, v.w};
  float o[4];
  #pragma unroll
  for (int j = 0; j < 4; ++j) {
    int cc = c + j;
    float mean = stats[cc] * invN;
    float var = stats[HH + cc] * invN - mean * mean;
    float rs = rsqrtf(var + 1e-5f);
    float val = (vv[j] - mean) * rs * g[cc] + b[cc];
    val = fmaxf(val, 0.f);
    if (res) val += res[i + j];
    o[j] = val;
  }
  float4 yo; ushort4 bo;
  yo.x = o[0]; yo.y = o[1]; yo.z = o[2]; yo.w = o[3];
  bo.x = f2bf(o[0]); bo.y = f2bf(o[1]); bo.z = f2bf(o[2]); bo.w = f2bf(o[3]);
  *reinterpret_cast<float4*>(y + i) = yo;
  *reinterpret_cast<ushort4*>(ybf + i) = bo;
}

// ---------------- pooling ----------------
__global__ void k_pool(const float* __restrict__ h, const int* __restrict__ batch,
                       float* __restrict__ gsum, float* __restrict__ gmax) {
  int c = threadIdx.x;
  int r0 = blockIdx.x * 512, r1 = min(r0 + 512, NN);
  if (r0 >= r1) return;
  int curg = batch[r0];
  float s = 0.f, mx = 0.f;
  for (int r = r0; r < r1; ++r) {
    int g = batch[r];
    if (g != curg) {
      atomicAdd(&gsum[curg * HH + c], s);
      atomicMax((int*)&gmax[curg * HH + c], __float_as_int(mx));
      s = 0.f; mx = 0.f; curg = g;
    }
    float v = h[(size_t)r * HH + c];
    s += v; mx = fmaxf(mx, v);
  }
  atomicAdd(&gsum[curg * HH + c], s);
  atomicMax((int*)&gmax[curg * HH + c], __float_as_int(mx));
}
__global__ void k_buildz(const float* __restrict__ gsum, const float* __restrict__ gmax,
                         const int* __restrict__ start, const float* __restrict__ gf,
                         float* __restrict__ z) {
  int g = blockIdx.x;
  float invc = 1.f / (float)(start[g + 1] - start[g]);
  for (int c = threadIdx.x; c < 800; c += 256) {
    float v;
    if (c < 256)      v = gsum[g * HH + c] * invc;
    else if (c < 512) v = gmax[g * HH + (c - 256)];
    else if (c < 768) v = gsum[g * HH + (c - 512)];
    else              v = gf[g * NGFD + (c - 768)];
    z[g * 800 + c] = v;
  }
}

// ---------------- classifier: 64-col tile per block, fused BN+relu ----------------
__global__ __launch_bounds__(256) void k_linbn(const float* __restrict__ zin,
                                               const float* __restrict__ W,
                                               const float* __restrict__ g,
                                               const float* __restrict__ be,
                                               float* __restrict__ zout, int K, int OC) {
  __shared__ float zs[64][128];
  __shared__ float ps[4][64], pq[4][64], scs[64], shs[64];
  int t = threadIdx.x;
  int jl = t & 63, q = t >> 6;
  int j = blockIdx.x * 64 + jl;
  float acc[16];
  #pragma unroll
  for (int r = 0; r < 16; ++r) acc[r] = 0.f;

  for (int kc = 0; kc < K; kc += 128) {
    for (int idx = t; idx < 64 * 128; idx += 256) {
      int r = idx >> 7, k = idx & 127;
      zs[r][k] = (kc + k < K) ? zin[(size_t)r * K + kc + k] : 0.f;
    }
    __syncthreads();
    int kmax = min(128, K - kc);
    for (int k = 0; k < kmax; ++k) {
      float wv = W[(size_t)(kc + k) * OC + j];
      #pragma unroll
      for (int rr = 0; rr < 16; ++rr) acc[rr] += zs[q * 16 + rr][k] * wv;
    }
    __syncthreads();
  }
  float s = 0.f, sq = 0.f;
  #pragma unroll
  for (int rr = 0; rr < 16; ++rr) { s += acc[rr]; sq += acc[rr] * acc[rr]; }
  ps[q][jl] = s; pq[q][jl] = sq;
  __syncthreads();
  if (t < 64) {
    float S = ps[0][t] + ps[1][t] + ps[2][t] + ps[3][t];
    float Q = pq[0][t] + pq[1][t] + pq[2][t] + pq[3][t];
    float mu = S * (1.f / 64.f);
    float var = Q * (1.f / 64.f) - mu * mu;
    float rs = rsqrtf(var + 1e-5f);
    float scv = rs * g[blockIdx.x * 64 + t];
    scs[t] = scv;
    shs[t] = be[blockIdx.x * 64 + t] - mu * scv;
  }
  __syncthreads();
  float scv = scs[jl], shv = shs[jl];
  #pragma unroll
  for (int rr = 0; rr < 16; ++rr)
    zout[(size_t)(q * 16 + rr) * OC + j] = fmaxf(acc[rr] * scv + shv, 0.f);
}

__global__ void k_final(const float* __restrict__ z2, const float* __restrict__ W3,
                        const float* __restrict__ b3, float* __restrict__ out) {
  int t = threadIdx.x;
  if (t >= 128) return;
  int i = t >> 1, j = t & 1;
  float acc = b3[j];
  for (int k = 0; k < 256; ++k) acc += z2[i * 256 + k] * W3[k * 2 + j];
  out[i * 2 + j] = acc;
}

extern "C" void kernel_launch(void* const* d_in, const int* in_sizes, int n_in,
                              void* d_out, int out_size, void* d_ws, size_t ws_size,
                              hipStream_t stream) {
  const float* x      = (const float*)d_in[0];
  const int*   ei     = (const int*)d_in[1];
  const int*   batch  = (const int*)d_in[2];
  const float* gf     = (const float*)d_in[3];
  const float* W_enc  = (const float*)d_in[4];
  const float* g_enc  = (const float*)d_in[6];
  const float* be_enc = (const float*)d_in[7];
  const float* Wg     = (const float*)d_in[8];
  const float* att_s  = (const float*)d_in[9];
  const float* att_d  = (const float*)d_in[10];
  const float* bn_g   = (const float*)d_in[12];
  const float* bn_b   = (const float*)d_in[13];
  const float* W1     = (const float*)d_in[14];
  const float* g1     = (const float*)d_in[16];
  const float* be1    = (const float*)d_in[17];
  const float* W2     = (const float*)d_in[18];
  const float* g2     = (const float*)d_in[20];
  const float* be2    = (const float*)d_in[21];
  const float* W3     = (const float*)d_in[22];
  const float* b3     = (const float*)d_in[23];
  float* out = (float*)d_out;

  char* w = (char*)d_ws;
  auto alloc = [&](size_t bytes) { char* p = w; w += (bytes + 255) & ~(size_t)255; return p; };
  float*          A    = (float*)alloc((size_t)MPAD * HH * 4);
  float*          Cc   = (float*)alloc((size_t)MPAD * HH * 4);
  unsigned short* A_bf = (unsigned short*)alloc((size_t)MPAD * HH * 2);
  unsigned short* hp   = (unsigned short*)alloc((size_t)MPAD * HH * 2);
  float* asn  = (float*)alloc((size_t)NN * 8 * 4);
  float* adn  = (float*)alloc((size_t)NN * 8 * 4);
  int*   deg  = (int*)alloc((size_t)NN * 4);
  int*   offs = (int*)alloc((size_t)(NN + 1) * 4);
  int*   cur  = (int*)alloc((size_t)NN * 4);
  int*   ssrc = (int*)alloc((size_t)EP * 4);
  float* pst  = (float*)alloc((size_t)196 * 512 * 4);
  float* stats= (float*)alloc(512 * 4);
  int*   aux  = (int*)alloc(64 * 4);
  int*   start= (int*)alloc(65 * 4);
  unsigned short* WencT = (unsigned short*)alloc((size_t)HH * FIN * 2);
  unsigned short* WgT   = (unsigned short*)alloc((size_t)4 * HH * HH * 2);
  float* gsum = (float*)alloc((size_t)GG * HH * 4);
  float* gmax = (float*)alloc((size_t)GG * HH * 4);
  float* zb   = (float*)alloc((size_t)GG * 800 * 4);
  float* z1   = (float*)alloc((size_t)GG * 512 * 4);
  float* z2   = (float*)alloc((size_t)GG * 256 * 4);

  unsigned short* x_bf = (unsigned short*)Cc;  // alias: Cc dead until layer-0 aggregation

  const int* e_src = ei;
  const int* e_dst = ei + EE;

  // ---- CSR build ----
  k_init_deg<<<196, 256, 0, stream>>>(deg);
  k_hist<<<1563, 256, 0, stream>>>(e_dst, deg);
  k_scan1<<<49, 256, 0, stream>>>(deg, offs, aux);
  k_scan2<<<1, 64, 0, stream>>>(aux, 49);
  k_scan3<<<49, 256, 0, stream>>>(offs, aux);
  hipMemcpyAsync(cur, offs, (size_t)NN * 4, hipMemcpyDeviceToDevice, stream);
  k_scatter<<<1563, 256, 0, stream>>>(e_src, e_dst, cur, ssrc);
  k_scatter_self<<<196, 256, 0, stream>>>(cur, ssrc);
  k_bounds<<<1, 128, 0, stream>>>(batch, start);

  // ---- prep ----
  k_prepW<<<dim3(8, 2, 1), 256, 0, stream>>>(W_enc, WencT, FIN, HH);
  k_prepW<<<dim3(8, 8, 4), 256, 0, stream>>>(Wg, WgT, HH, HH);
  k_cvt_x<<<3125, 256, 0, stream>>>(x, x_bf);

  dim3 mg(MPAD / 128, 2);

  // ---- node encoder ----
  k_mfma<<<mg, 256, 0, stream>>>(x_bf, WencT, hp, FIN);
  k_cstat_bf<<<196, 256, 0, stream>>>(hp, pst);
  k_redstat<<<2, 256, 0, stream>>>(pst, stats, 196);
  k_bnap_bf<<<12500, 256, 0, stream>>>(hp, stats, g_enc, be_enc, A, A_bf);

  // ---- GAT layers ----
  for (int l = 0; l < 4; ++l) {
    k_mfma<<<mg, 256, 0, stream>>>(A_bf, WgT + (size_t)l * HH * HH, hp, HH);
    k_attdot<<<12500, 256, 0, stream>>>(hp, att_s + l * HH, att_d + l * HH, asn, adn);
    k_gat_agg<<<12500, 256, 0, stream>>>(offs, ssrc, asn, adn, hp, Cc);
    k_cstat_f32<<<196, 256, 0, stream>>>(Cc, pst);
    k_redstat<<<2, 256, 0, stream>>>(pst, stats, 196);
    k_bnap_f32<<<12500, 256, 0, stream>>>(Cc, stats, bn_g + l * HH, bn_b + l * HH,
                                          (l == 2) ? A : nullptr, A, A_bf);
  }

  // ---- pooling + classifier ----
  hipMemsetAsync(gsum, 0, (size_t)GG * HH * 4, stream);
  hipMemsetAsync(gmax, 0, (size_t)GG * HH * 4, stream);
  k_pool<<<(NN + 511) / 512, 256, 0, stream>>>(A, batch, gsum, gmax);
  k_buildz<<<GG, 256, 0, stream>>>(gsum, gmax, start, gf, zb);
  k_linbn<<<8, 256, 0, stream>>>(zb, W1, g1, be1, z1, 800, 512);
  k_linbn<<<4, 256, 0, stream>>>(z1, W2, g2, be2, z2, 512, 256);
  k_final<<<1, 128, 0, stream>>>(z2, W3, b3, out);
}

// Round 7
// 1780.465 us; speedup vs baseline: 1.3631x; 1.0362x over previous
//
#include <hip/hip_runtime.h>

#define NN 50000
#define MPAD 50048
#define EE 400000
#define EP 450000
#define FIN 64
#define HH 256
#define GG 64
#define NGFD 32

typedef __attribute__((ext_vector_type(8))) _Float16 f16x8;
typedef __attribute__((ext_vector_type(4))) float f32x4;

__device__ __forceinline__ unsigned short f2h(float f) {
  _Float16 h = (_Float16)f;                       // RTN
  return __builtin_bit_cast(unsigned short, h);
}
__device__ __forceinline__ float h2f(unsigned short s) {
  _Float16 h = __builtin_bit_cast(_Float16, s);
  return (float)h;
}

// ---------------- CSR build ----------------
__global__ void k_init_deg(int* deg) {
  int i = blockIdx.x * 256 + threadIdx.x;
  if (i < NN) deg[i] = 1;  // self loop
}
__global__ void k_hist(const int* __restrict__ dst, int* __restrict__ deg) {
  int e = blockIdx.x * 256 + threadIdx.x;
  if (e < EE) atomicAdd(&deg[dst[e]], 1);
}
__global__ void k_scan1(const int* __restrict__ deg, int* __restrict__ offs, int* __restrict__ aux) {
  __shared__ int sd[256];
  int b = blockIdx.x, t = threadIdx.x;
  int base = b * 1024 + t * 4;
  int v0 = 0, v1 = 0, v2 = 0, v3 = 0;
  if (base + 0 < NN) v0 = deg[base + 0];
  if (base + 1 < NN) v1 = deg[base + 1];
  if (base + 2 < NN) v2 = deg[base + 2];
  if (base + 3 < NN) v3 = deg[base + 3];
  sd[t] = v0 + v1 + v2 + v3;
  __syncthreads();
  for (int off = 1; off < 256; off <<= 1) {
    int x = (t >= off) ? sd[t - off] : 0;
    __syncthreads();
    sd[t] += x;
    __syncthreads();
  }
  if (t == 255) aux[b] = sd[255];
  int run = (t == 0) ? 0 : sd[t - 1];
  if (base + 0 < NN) offs[base + 0] = run; run += v0;
  if (base + 1 < NN) offs[base + 1] = run; run += v1;
  if (base + 2 < NN) offs[base + 2] = run; run += v2;
  if (base + 3 < NN) offs[base + 3] = run;
}
__global__ void k_scan2(int* aux, int nb) {
  if (threadIdx.x == 0 && blockIdx.x == 0) {
    int s = 0;
    for (int i = 0; i < nb; ++i) { int t = aux[i]; aux[i] = s; s += t; }
    aux[nb] = s;
  }
}
__global__ void k_scan3(int* __restrict__ offs, const int* __restrict__ aux) {
  int b = blockIdx.x, t = threadIdx.x;
  int base = b * 1024 + t * 4;
  int add = aux[b];
  #pragma unroll
  for (int i = 0; i < 4; ++i)
    if (base + i < NN) offs[base + i] += add;
  if (b == 0 && t == 0) offs[NN] = aux[gridDim.x];
}
__global__ void k_scatter(const int* __restrict__ srcA, const int* __restrict__ dstA,
                          int* __restrict__ cur, int* __restrict__ ssrc) {
  int e = blockIdx.x * 256 + threadIdx.x;
  if (e < EE) { int p = atomicAdd(&cur[dstA[e]], 1); ssrc[p] = srcA[e]; }
}
__global__ void k_scatter_self(int* __restrict__ cur, int* __restrict__ ssrc) {
  int i = blockIdx.x * 256 + threadIdx.x;
  if (i < NN) { int p = atomicAdd(&cur[i], 1); ssrc[p] = i; }
}

// ---------------- graph boundaries via binary search (batch is sorted) ----------------
__global__ void k_bounds(const int* __restrict__ batch, int* __restrict__ start) {
  int g = threadIdx.x;
  if (g > GG) return;
  int lo = 0, hi = NN;
  while (lo < hi) { int mid = (lo + hi) >> 1; if (batch[mid] < g) lo = mid + 1; else hi = mid; }
  start[g] = lo;
}

// ---------------- weight prep: W[K][N] f32 -> WT[N][K] fp16 ----------------
__global__ void k_prepW(const float* __restrict__ W, unsigned short* __restrict__ WT, int K, int N) {
  __shared__ float tile[32][33];
  int l = blockIdx.z;
  const float* Wp = W + (size_t)l * K * N;
  unsigned short* Tp = WT + (size_t)l * K * N;
  int n0 = blockIdx.x * 32, k0 = blockIdx.y * 32;
  int tx = threadIdx.x & 31, ty = threadIdx.x >> 5;  // 8 row-groups
  #pragma unroll
  for (int rr = 0; rr < 32; rr += 8) {
    int k = k0 + ty + rr, n = n0 + tx;
    if (k < K && n < N) tile[ty + rr][tx] = Wp[(size_t)k * N + n];
  }
  __syncthreads();
  #pragma unroll
  for (int rr = 0; rr < 32; rr += 8) {
    int n = n0 + ty + rr, k = k0 + tx;
    if (n < N && k < K) Tp[(size_t)n * K + k] = f2h(tile[tx][ty + rr]);
  }
}

__global__ void k_cvt_x(const float* __restrict__ x, unsigned short* __restrict__ xb) {
  size_t i = ((size_t)blockIdx.x * 256 + threadIdx.x) * 4;
  if (i >= (size_t)NN * FIN) return;
  float4 v = *reinterpret_cast<const float4*>(x + i);
  ushort4 o;
  o.x = f2h(v.x); o.y = f2h(v.y); o.z = f2h(v.z); o.w = f2h(v.w);
  *reinterpret_cast<ushort4*>(xb + i) = o;
}

// ---------------- fp16 MFMA GEMM: writes f32 (Cf) + fp16 (Cb) ----------------
// 128x128 tile, 4 waves of 64x64, BK=64, global_load_lds w/ pre-swizzled source,
// XOR-swizzled ds_read_b128.
__global__ __launch_bounds__(256) void k_mfma(const unsigned short* __restrict__ A,
                                              const unsigned short* __restrict__ BT,
                                              float* __restrict__ Cf,
                                              unsigned short* __restrict__ Cb, int K) {
  __shared__ unsigned short As[128 * 64];
  __shared__ unsigned short Bs[128 * 64];
  const int t = threadIdx.x;
  const int w = t >> 6, l = t & 63;
  const int row0 = blockIdx.x * 128;
  const int col0 = blockIdx.y * 128;
  const int wm = w & 1, wn = w >> 1;

  f32x4 acc[4][4];
  #pragma unroll
  for (int i = 0; i < 4; ++i)
    #pragma unroll
    for (int j = 0; j < 4; ++j) acc[i][j] = (f32x4){0.f, 0.f, 0.f, 0.f};

  const int lrow = w * 8 + (l >> 3);                      // row within 32-row round
  const int ksrc_sh = ((l & 7) ^ (lrow & 7)) << 3;        // source k offset (inverse swizzle)

  for (int k0 = 0; k0 < K; k0 += 64) {
    #pragma unroll
    for (int rd = 0; rd < 4; ++rd) {
      int r = rd * 32 + lrow;
      const unsigned short* ga = A + (size_t)(row0 + r) * K + k0 + ksrc_sh;
      __builtin_amdgcn_global_load_lds(
          (const __attribute__((address_space(1))) void*)ga,
          (__attribute__((address_space(3))) void*)(As + (size_t)(rd * 32 + w * 8) * 64),
          16, 0, 0);
    }
    #pragma unroll
    for (int rd = 0; rd < 4; ++rd) {
      int r = rd * 32 + lrow;
      const unsigned short* gb = BT + (size_t)(col0 + r) * K + k0 + ksrc_sh;
      __builtin_amdgcn_global_load_lds(
          (const __attribute__((address_space(1))) void*)gb,
          (__attribute__((address_space(3))) void*)(Bs + (size_t)(rd * 32 + w * 8) * 64),
          16, 0, 0);
    }
    __syncthreads();

    const char* AsB = (const char*)As;
    const char* BsB = (const char*)Bs;
    #pragma unroll
    for (int ks = 0; ks < 2; ++ks) {
      f16x8 af[4], bfr[4];
      #pragma unroll
      for (int i = 0; i < 4; ++i) {
        int ar = wm * 64 + i * 16 + (l & 15);
        int ab = ar * 128 + ((ks * 64 + (l >> 4) * 16) ^ ((ar & 7) << 4));
        af[i] = *(const f16x8*)(AsB + ab);
        int br = wn * 64 + i * 16 + (l & 15);
        int bb = br * 128 + ((ks * 64 + (l >> 4) * 16) ^ ((br & 7) << 4));
        bfr[i] = *(const f16x8*)(BsB + bb);
      }
      #pragma unroll
      for (int i = 0; i < 4; ++i)
        #pragma unroll
        for (int j = 0; j < 4; ++j)
          acc[i][j] = __builtin_amdgcn_mfma_f32_16x16x32_f16(af[i], bfr[j], acc[i][j], 0, 0, 0);
    }
    __syncthreads();
  }

  // epilogue: C/D layout col=lane&15, row=(lane>>4)*4+r
  #pragma unroll
  for (int i = 0; i < 4; ++i) {
    int rbase = row0 + wm * 64 + i * 16 + ((l >> 4) * 4);
    #pragma unroll
    for (int j = 0; j < 4; ++j) {
      int c = col0 + wn * 64 + j * 16 + (l & 15);
      #pragma unroll
      for (int r = 0; r < 4; ++r) {
        int rr = rbase + r;
        if (rr < NN) {
          float v = acc[i][j][r];
          Cf[(size_t)rr * HH + c] = v;
          Cb[(size_t)rr * HH + c] = f2h(v);
        }
      }
    }
  }
}

// ---------------- attention dots from f32 GEMM output ----------------
__global__ void k_attdot(const float* __restrict__ hpf, const float* __restrict__ a_s,
                         const float* __restrict__ a_d, float* __restrict__ asn,
                         float* __restrict__ adn) {
  int lane = threadIdx.x & 63;
  int n = blockIdx.x * 4 + (threadIdx.x >> 6);
  if (n >= NN) return;
  float4 v = *reinterpret_cast<const float4*>(hpf + (size_t)n * HH + lane * 4);
  float4 s4 = *reinterpret_cast<const float4*>(a_s + lane * 4);
  float4 d4 = *reinterpret_cast<const float4*>(a_d + lane * 4);
  float ps = v.x * s4.x + v.y * s4.y + v.z * s4.z + v.w * s4.w;
  float pd = v.x * d4.x + v.y * d4.y + v.z * d4.z + v.w * d4.w;
  ps += __shfl_xor(ps, 1); ps += __shfl_xor(ps, 2); ps += __shfl_xor(ps, 4);
  pd += __shfl_xor(pd, 1); pd += __shfl_xor(pd, 2); pd += __shfl_xor(pd, 4);
  if ((lane & 7) == 0) {
    asn[n * 8 + (lane >> 3)] = ps;
    adn[n * 8 + (lane >> 3)] = pd;
  }
}

// ---------------- GAT edge softmax + aggregate (fp16 gather) ----------------
__global__ __launch_bounds__(256) void k_gat_agg(const int* __restrict__ offs, const int* __restrict__ ssrc,
                                                 const float* __restrict__ asn, const float* __restrict__ adn,
                                                 const unsigned short* __restrict__ hp,
                                                 float* __restrict__ outp) {
  int lane = threadIdx.x & 63;
  int n = blockIdx.x * 4 + (threadIdx.x >> 6);
  if (n >= NN) return;
  int hd = lane >> 3;
  float adh = adn[n * 8 + hd];
  int e0 = offs[n], e1 = offs[n + 1];
  float m = -1e30f, den = 0.f;
  for (int k = e0; k < e1; ++k) {
    int s = ssrc[k];
    float e = asn[s * 8 + hd] + adh;
    e = (e > 0.f) ? e : 0.2f * e;
    if (e > m) { den *= __expf(m - e); m = e; }
    den += __expf(e - m);
  }
  float rden = 1.f / den;
  float4 acc = make_float4(0.f, 0.f, 0.f, 0.f);
  for (int k = e0; k < e1; ++k) {
    int s = ssrc[k];
    float e = asn[s * 8 + hd] + adh;
    e = (e > 0.f) ? e : 0.2f * e;
    float al = __expf(e - m) * rden;
    ushort4 hv = *reinterpret_cast<const ushort4*>(hp + (size_t)s * HH + lane * 4);
    acc.x += al * h2f(hv.x); acc.y += al * h2f(hv.y);
    acc.z += al * h2f(hv.z); acc.w += al * h2f(hv.w);
  }
  *reinterpret_cast<float4*>(outp + (size_t)n * HH + lane * 4) = acc;
}

// ---------------- BN stats (partials, no atomics) ----------------
__global__ void k_cstat_f32(const float* __restrict__ x, float* __restrict__ pst) {
  int c = threadIdx.x, b = blockIdx.x;
  int r0 = b * 256, r1 = min(r0 + 256, NN);
  float s = 0.f, q = 0.f;
  for (int r = r0; r < r1; ++r) {
    float v = x[(size_t)r * HH + c];
    s += v; q += v * v;
  }
  pst[b * 512 + c] = s;
  pst[b * 512 + 256 + c] = q;
}
__global__ void k_redstat(const float* __restrict__ pst, float* __restrict__ stats, int nb) {
  int c = blockIdx.x * 256 + threadIdx.x;  // 512 total
  float s = 0.f;
  for (int b = 0; b < nb; ++b) s += pst[b * 512 + c];
  stats[c] = s;
}

// ---------------- BN apply + relu (+res), writes f32 + fp16 ----------------
__global__ void k_bnap_f32(const float* __restrict__ x, const float* __restrict__ stats,
                           const float* __restrict__ g, const float* __restrict__ b,
                           const float* res, float* y, unsigned short* __restrict__ ybf) {
  size_t i = ((size_t)blockIdx.x * 256 + threadIdx.x) * 4;
  if (i >= (size_t)NN * HH) return;
  float4 v = *reinterpret_cast<const float4*>(x + i);
  int c = (int)(i & 255);
  const float invN = 1.f / (float)NN;
  float vv[4] = {v.x, v.y, v.z, v.w};
  float o[4];
  #pragma unroll
  for (int j = 0; j < 4; ++j) {
    int cc = c + j;
    float mean = stats[cc] * invN;
    float var = stats[HH + cc] * invN - mean * mean;
    float rs = rsqrtf(var + 1e-5f);
    float val = (vv[j] - mean) * rs * g[cc] + b[cc];
    val = fmaxf(val, 0.f);
    if (res) val += res[i + j];
    o[j] = val;
  }
  float4 yo; ushort4 bo;
  yo.x = o[0]; yo.y = o[1]; yo.z = o[2]; yo.w = o[3];
  bo.x = f2h(o[0]); bo.y = f2h(o[1]); bo.z = f2h(o[2]); bo.w = f2h(o[3]);
  *reinterpret_cast<float4*>(y + i) = yo;
  *reinterpret_cast<ushort4*>(ybf + i) = bo;
}

// ---------------- pooling ----------------
__global__ void k_pool(const float* __restrict__ h, const int* __restrict__ batch,
                       float* __restrict__ gsum, float* __restrict__ gmax) {
  int c = threadIdx.x;
  int r0 = blockIdx.x * 512, r1 = min(r0 + 512, NN);
  if (r0 >= r1) return;
  int curg = batch[r0];
  float s = 0.f, mx = 0.f;
  for (int r = r0; r < r1; ++r) {
    int g = batch[r];
    if (g != curg) {
      atomicAdd(&gsum[curg * HH + c], s);
      atomicMax((int*)&gmax[curg * HH + c], __float_as_int(mx));
      s = 0.f; mx = 0.f; curg = g;
    }
    float v = h[(size_t)r * HH + c];
    s += v; mx = fmaxf(mx, v);
  }
  atomicAdd(&gsum[curg * HH + c], s);
  atomicMax((int*)&gmax[curg * HH + c], __float_as_int(mx));
}
__global__ void k_buildz(const float* __restrict__ gsum, const float* __restrict__ gmax,
                         const int* __restrict__ start, const float* __restrict__ gf,
                         float* __restrict__ z) {
  int g = blockIdx.x;
  float invc = 1.f / (float)(start[g + 1] - start[g]);
  for (int c = threadIdx.x; c < 800; c += 256) {
    float v;
    if (c < 256)      v = gsum[g * HH + c] * invc;
    else if (c < 512) v = gmax[g * HH + (c - 256)];
    else if (c < 768) v = gsum[g * HH + (c - 512)];
    else              v = gf[g * NGFD + (c - 768)];
    z[g * 800 + c] = v;
  }
}

// ---------------- classifier v2: 16-col tile/block, 16 row-groups, fused BN+relu ----------------
__global__ __launch_bounds__(256) void k_linbn(const float* __restrict__ zin,
                                               const float* __restrict__ W,
                                               const float* __restrict__ g,
                                               const float* __restrict__ be,
                                               float* __restrict__ zout, int K, int OC) {
  __shared__ float zs[64][132];
  __shared__ float reds[16][16], redq[16][16], scs[16], shs[16];
  int t = threadIdx.x;
  int jl = t & 15, rq = t >> 4;           // 16 cols, 16 row-groups (4 rows each)
  int j = blockIdx.x * 16 + jl;
  float acc[4] = {0.f, 0.f, 0.f, 0.f};

  for (int kc = 0; kc < K; kc += 128) {
    int kmax = min(128, K - kc);
    for (int idx = t; idx < 64 * 128; idx += 256) {
      int r = idx >> 7, k = idx & 127;
      zs[r][k] = (k < kmax) ? zin[(size_t)r * K + kc + k] : 0.f;
    }
    __syncthreads();
    int k = 0;
    for (; k + 8 <= kmax; k += 8) {
      float wv[8];
      #pragma unroll
      for (int u = 0; u < 8; ++u) wv[u] = W[(size_t)(kc + k + u) * OC + j];
      #pragma unroll
      for (int u = 0; u < 8; ++u)
        #pragma unroll
        for (int rr = 0; rr < 4; ++rr) acc[rr] += zs[rq * 4 + rr][k + u] * wv[u];
    }
    for (; k < kmax; ++k) {
      float wv = W[(size_t)(kc + k) * OC + j];
      #pragma unroll
      for (int rr = 0; rr < 4; ++rr) acc[rr] += zs[rq * 4 + rr][k] * wv;
    }
    __syncthreads();
  }

  float s = 0.f, q = 0.f;
  #pragma unroll
  for (int rr = 0; rr < 4; ++rr) { s += acc[rr]; q += acc[rr] * acc[rr]; }
  reds[rq][jl] = s; redq[rq][jl] = q;
  __syncthreads();
  if (t < 16) {
    float S = 0.f, Q = 0.f;
    #pragma unroll
    for (int gq = 0; gq < 16; ++gq) { S += reds[gq][t]; Q += redq[gq][t]; }
    float mu = S * (1.f / 64.f);
    float var = Q * (1.f / 64.f) - mu * mu;
    float rs = rsqrtf(var + 1e-5f);
    float scv = rs * g[blockIdx.x * 16 + t];
    scs[t] = scv;
    shs[t] = be[blockIdx.x * 16 + t] - mu * scv;
  }
  __syncthreads();
  float scv = scs[jl], shv = shs[jl];
  #pragma unroll
  for (int rr = 0; rr < 4; ++rr)
    zout[(size_t)(rq * 4 + rr) * OC + j] = fmaxf(acc[rr] * scv + shv, 0.f);
}

__global__ void k_final(const float* __restrict__ z2, const float* __restrict__ W3,
                        const float* __restrict__ b3, float* __restrict__ out) {
  int t = threadIdx.x;
  if (t >= 128) return;
  int i = t >> 1, j = t & 1;
  float acc = b3[j];
  for (int k = 0; k < 256; ++k) acc += z2[i * 256 + k] * W3[k * 2 + j];
  out[i * 2 + j] = acc;
}

extern "C" void kernel_launch(void* const* d_in, const int* in_sizes, int n_in,
                              void* d_out, int out_size, void* d_ws, size_t ws_size,
                              hipStream_t stream) {
  const float* x      = (const float*)d_in[0];
  const int*   ei     = (const int*)d_in[1];
  const int*   batch  = (const int*)d_in[2];
  const float* gf     = (const float*)d_in[3];
  const float* W_enc  = (const float*)d_in[4];
  const float* g_enc  = (const float*)d_in[6];
  const float* be_enc = (const float*)d_in[7];
  const float* Wg     = (const float*)d_in[8];
  const float* att_s  = (const float*)d_in[9];
  const float* att_d  = (const float*)d_in[10];
  const float* bn_g   = (const float*)d_in[12];
  const float* bn_b   = (const float*)d_in[13];
  const float* W1     = (const float*)d_in[14];
  const float* g1     = (const float*)d_in[16];
  const float* be1    = (const float*)d_in[17];
  const float* W2     = (const float*)d_in[18];
  const float* g2     = (const float*)d_in[20];
  const float* be2    = (const float*)d_in[21];
  const float* W3     = (const float*)d_in[22];
  const float* b3     = (const float*)d_in[23];
  float* out = (float*)d_out;

  char* w = (char*)d_ws;
  auto alloc = [&](size_t bytes) { char* p = w; w += (bytes + 255) & ~(size_t)255; return p; };
  float*          A    = (float*)alloc((size_t)MPAD * HH * 4);
  float*          Cc   = (float*)alloc((size_t)MPAD * HH * 4);   // f32 GEMM out
  unsigned short* A_bf = (unsigned short*)alloc((size_t)MPAD * HH * 2);
  unsigned short* hp   = (unsigned short*)alloc((size_t)MPAD * HH * 2);
  unsigned short* x_bf = (unsigned short*)alloc((size_t)MPAD * FIN * 2);
  float* asn  = (float*)alloc((size_t)NN * 8 * 4);
  float* adn  = (float*)alloc((size_t)NN * 8 * 4);
  int*   deg  = (int*)alloc((size_t)NN * 4);
  int*   offs = (int*)alloc((size_t)(NN + 1) * 4);
  int*   cur  = (int*)alloc((size_t)NN * 4);
  int*   ssrc = (int*)alloc((size_t)EP * 4);
  float* pst  = (float*)alloc((size_t)196 * 512 * 4);
  float* stats= (float*)alloc(512 * 4);
  int*   aux  = (int*)alloc(64 * 4);
  int*   start= (int*)alloc(65 * 4);
  unsigned short* WencT = (unsigned short*)alloc((size_t)HH * FIN * 2);
  unsigned short* WgT   = (unsigned short*)alloc((size_t)4 * HH * HH * 2);
  float* gsum = (float*)alloc((size_t)GG * HH * 4);
  float* gmax = (float*)alloc((size_t)GG * HH * 4);
  float* zb   = (float*)alloc((size_t)GG * 800 * 4);
  float* z1   = (float*)alloc((size_t)GG * 512 * 4);
  float* z2   = (float*)alloc((size_t)GG * 256 * 4);

  const int* e_src = ei;
  const int* e_dst = ei + EE;

  // ---- CSR build ----
  k_init_deg<<<196, 256, 0, stream>>>(deg);
  k_hist<<<1563, 256, 0, stream>>>(e_dst, deg);
  k_scan1<<<49, 256, 0, stream>>>(deg, offs, aux);
  k_scan2<<<1, 64, 0, stream>>>(aux, 49);
  k_scan3<<<49, 256, 0, stream>>>(offs, aux);
  hipMemcpyAsync(cur, offs, (size_t)NN * 4, hipMemcpyDeviceToDevice, stream);
  k_scatter<<<1563, 256, 0, stream>>>(e_src, e_dst, cur, ssrc);
  k_scatter_self<<<196, 256, 0, stream>>>(cur, ssrc);
  k_bounds<<<1, 128, 0, stream>>>(batch, start);

  // ---- prep ----
  k_prepW<<<dim3(8, 2, 1), 256, 0, stream>>>(W_enc, WencT, FIN, HH);
  k_prepW<<<dim3(8, 8, 4), 256, 0, stream>>>(Wg, WgT, HH, HH);
  k_cvt_x<<<3125, 256, 0, stream>>>(x, x_bf);

  dim3 mg(MPAD / 128, 2);

  // ---- node encoder ----
  k_mfma<<<mg, 256, 0, stream>>>(x_bf, WencT, Cc, hp, FIN);
  k_cstat_f32<<<196, 256, 0, stream>>>(Cc, pst);
  k_redstat<<<2, 256, 0, stream>>>(pst, stats, 196);
  k_bnap_f32<<<12500, 256, 0, stream>>>(Cc, stats, g_enc, be_enc, nullptr, A, A_bf);

  // ---- GAT layers ----
  for (int l = 0; l < 4; ++l) {
    k_mfma<<<mg, 256, 0, stream>>>(A_bf, WgT + (size_t)l * HH * HH, Cc, hp, HH);
    k_attdot<<<12500, 256, 0, stream>>>(Cc, att_s + l * HH, att_d + l * HH, asn, adn);
    k_gat_agg<<<12500, 256, 0, stream>>>(offs, ssrc, asn, adn, hp, Cc);
    k_cstat_f32<<<196, 256, 0, stream>>>(Cc, pst);
    k_redstat<<<2, 256, 0, stream>>>(pst, stats, 196);
    k_bnap_f32<<<12500, 256, 0, stream>>>(Cc, stats, bn_g + l * HH, bn_b + l * HH,
                                          (l == 2) ? A : nullptr, A, A_bf);
  }

  // ---- pooling + classifier ----
  hipMemsetAsync(gsum, 0, (size_t)GG * HH * 4, stream);
  hipMemsetAsync(gmax, 0, (size_t)GG * HH * 4, stream);
  k_pool<<<(NN + 511) / 512, 256, 0, stream>>>(A, batch, gsum, gmax);
  k_buildz<<<GG, 256, 0, stream>>>(gsum, gmax, start, gf, zb);
  k_linbn<<<32, 256, 0, stream>>>(zb, W1, g1, be1, z1, 800, 512);
  k_linbn<<<16, 256, 0, stream>>>(z1, W2, g2, be2, z2, 512, 256);
  k_final<<<1, 128, 0, stream>>>(z2, W3, b3, out);
}